// Round 1
// baseline (443.720 us; speedup 1.0000x reference)
//
#include <hip/hip_runtime.h>

// QReLU: out = x > 0 ? x : -1.99f * x
// fp32 in/out, 268,435,456 elements (divisible by 4 -> clean float4 path).
// Pure streaming memory-bound kernel: float4 loads/stores, grid-stride,
// 2048 blocks x 256 threads (256 CU x 8 blocks/CU).

__global__ void qrelu_f4_kernel(const float4* __restrict__ x,
                                float4* __restrict__ out,
                                int n4) {
    const int stride = gridDim.x * blockDim.x;
    for (int i = blockIdx.x * blockDim.x + threadIdx.x; i < n4; i += stride) {
        float4 v = x[i];
        float4 r;
        r.x = v.x > 0.0f ? v.x : -1.99f * v.x;
        r.y = v.y > 0.0f ? v.y : -1.99f * v.y;
        r.z = v.z > 0.0f ? v.z : -1.99f * v.z;
        r.w = v.w > 0.0f ? v.w : -1.99f * v.w;
        out[i] = r;
    }
}

// Tail kernel only needed if n % 4 != 0 (not the case here, but keep it correct
// for any size).
__global__ void qrelu_tail_kernel(const float* __restrict__ x,
                                  float* __restrict__ out,
                                  int start, int n) {
    int i = start + blockIdx.x * blockDim.x + threadIdx.x;
    if (i < n) {
        float v = x[i];
        out[i] = v > 0.0f ? v : -1.99f * v;
    }
}

extern "C" void kernel_launch(void* const* d_in, const int* in_sizes, int n_in,
                              void* d_out, int out_size, void* d_ws, size_t ws_size,
                              hipStream_t stream) {
    const float* x = (const float*)d_in[0];
    float* out = (float*)d_out;
    const int n = in_sizes[0];

    const int n4 = n / 4;
    const int block = 256;
    int grid = (n4 + block - 1) / block;
    if (grid > 2048) grid = 2048;
    if (grid > 0) {
        qrelu_f4_kernel<<<grid, block, 0, stream>>>(
            (const float4*)x, (float4*)out, n4);
    }

    const int tail_start = n4 * 4;
    const int tail = n - tail_start;
    if (tail > 0) {
        qrelu_tail_kernel<<<(tail + block - 1) / block, block, 0, stream>>>(
            x, out, tail_start, n);
    }
}

// Round 2
// 403.480 us; speedup vs baseline: 1.0997x; 1.0997x over previous
//
#include <hip/hip_runtime.h>

// QReLU: out = x > 0 ? x : -1.99f * x
// fp32 in/out, 268,435,456 elements. Memory-bound streaming op.
//
// R2 change: 4x unrolled tile per block-iteration (4 independent float4
// loads in flight per wave before any store) to raise memory-level
// parallelism. Tile = 256 threads x 4 float4 = 1024 float4s = 16 KB.

#define BLOCK 256
#define TILE_F4 (BLOCK * 4)   // 1024 float4s per tile

__device__ __forceinline__ float4 qrelu4(float4 v) {
    float4 r;
    r.x = v.x > 0.0f ? v.x : -1.99f * v.x;
    r.y = v.y > 0.0f ? v.y : -1.99f * v.y;
    r.z = v.z > 0.0f ? v.z : -1.99f * v.z;
    r.w = v.w > 0.0f ? v.w : -1.99f * v.w;
    return r;
}

// Processes ntiles complete tiles of 1024 float4s each (no bounds checks).
__global__ void __launch_bounds__(BLOCK) qrelu_f4x4_kernel(
        const float4* __restrict__ x, float4* __restrict__ out, int ntiles) {
    for (int t = blockIdx.x; t < ntiles; t += gridDim.x) {
        const int base = t * TILE_F4 + threadIdx.x;
        // 4 independent loads issued back-to-back -> 4 outstanding per wave.
        float4 v0 = x[base];
        float4 v1 = x[base + BLOCK];
        float4 v2 = x[base + 2 * BLOCK];
        float4 v3 = x[base + 3 * BLOCK];
        out[base]             = qrelu4(v0);
        out[base + BLOCK]     = qrelu4(v1);
        out[base + 2 * BLOCK] = qrelu4(v2);
        out[base + 3 * BLOCK] = qrelu4(v3);
    }
}

// Scalar tail for any elements beyond the last complete tile.
__global__ void qrelu_tail_kernel(const float* __restrict__ x,
                                  float* __restrict__ out,
                                  int start, int n) {
    int i = start + blockIdx.x * blockDim.x + threadIdx.x;
    if (i < n) {
        float v = x[i];
        out[i] = v > 0.0f ? v : -1.99f * v;
    }
}

extern "C" void kernel_launch(void* const* d_in, const int* in_sizes, int n_in,
                              void* d_out, int out_size, void* d_ws, size_t ws_size,
                              hipStream_t stream) {
    const float* x = (const float*)d_in[0];
    float* out = (float*)d_out;
    const int n = in_sizes[0];

    const int n4 = n / 4;                 // complete float4s
    const int ntiles = n4 / TILE_F4;      // complete 1024-float4 tiles
    if (ntiles > 0) {
        int grid = ntiles < 2048 ? ntiles : 2048;
        qrelu_f4x4_kernel<<<grid, BLOCK, 0, stream>>>(
            (const float4*)x, (float4*)out, ntiles);
    }

    // Tail: elements not covered by complete tiles (none for this shape).
    const int tail_start = ntiles * TILE_F4 * 4;
    const int tail = n - tail_start;
    if (tail > 0) {
        qrelu_tail_kernel<<<(tail + BLOCK - 1) / BLOCK, BLOCK, 0, stream>>>(
            x, out, tail_start, n);
    }
}

// Round 3
// 373.762 us; speedup vs baseline: 1.1872x; 1.0795x over previous
//
#include <hip/hip_runtime.h>

// QReLU: out = x > 0 ? x : -1.99f * x
// fp32 in/out, 268,435,456 elements. Memory-bound streaming op.
//
// R3 changes vs R2 (403.5 us, 5.32 TB/s eff):
//  1. Non-temporal loads/stores (zero-reuse stream; skip cache allocate).
//  2. 8 independent float4 loads in flight per wave-iteration (was 4).

#define BLOCK 256
#define UNROLL 8
#define TILE_F4 (BLOCK * UNROLL)   // 2048 float4s = 32 KB per tile

typedef float f32x4 __attribute__((ext_vector_type(4)));

__device__ __forceinline__ f32x4 qrelu4(f32x4 v) {
    f32x4 r;
    r.x = v.x > 0.0f ? v.x : -1.99f * v.x;
    r.y = v.y > 0.0f ? v.y : -1.99f * v.y;
    r.z = v.z > 0.0f ? v.z : -1.99f * v.z;
    r.w = v.w > 0.0f ? v.w : -1.99f * v.w;
    return r;
}

__global__ void __launch_bounds__(BLOCK) qrelu_f4x8_nt_kernel(
        const f32x4* __restrict__ x, f32x4* __restrict__ out, int ntiles) {
    for (int t = blockIdx.x; t < ntiles; t += gridDim.x) {
        const int base = t * TILE_F4 + threadIdx.x;
        f32x4 v[UNROLL];
#pragma unroll
        for (int u = 0; u < UNROLL; ++u)
            v[u] = __builtin_nontemporal_load(&x[base + u * BLOCK]);
#pragma unroll
        for (int u = 0; u < UNROLL; ++u)
            __builtin_nontemporal_store(qrelu4(v[u]), &out[base + u * BLOCK]);
    }
}

// Scalar tail for any elements beyond the last complete tile.
__global__ void qrelu_tail_kernel(const float* __restrict__ x,
                                  float* __restrict__ out,
                                  int start, int n) {
    int i = start + blockIdx.x * blockDim.x + threadIdx.x;
    if (i < n) {
        float v = x[i];
        out[i] = v > 0.0f ? v : -1.99f * v;
    }
}

extern "C" void kernel_launch(void* const* d_in, const int* in_sizes, int n_in,
                              void* d_out, int out_size, void* d_ws, size_t ws_size,
                              hipStream_t stream) {
    const float* x = (const float*)d_in[0];
    float* out = (float*)d_out;
    const int n = in_sizes[0];

    const int n4 = n / 4;                 // complete float4s
    const int ntiles = n4 / TILE_F4;      // complete tiles
    if (ntiles > 0) {
        int grid = ntiles < 2048 ? ntiles : 2048;
        qrelu_f4x8_nt_kernel<<<grid, BLOCK, 0, stream>>>(
            (const f32x4*)x, (f32x4*)out, ntiles);
    }

    // Tail: elements not covered by complete tiles (none for this shape).
    const int tail_start = ntiles * TILE_F4 * 4;
    const int tail = n - tail_start;
    if (tail > 0) {
        qrelu_tail_kernel<<<(tail + BLOCK - 1) / BLOCK, BLOCK, 0, stream>>>(
            x, out, tail_start, n);
    }
}